// Round 7
// baseline (322.484 us; speedup 1.0000x reference)
//
#include <hip/hip_runtime.h>
#include <hip/hip_bf16.h>

typedef __attribute__((ext_vector_type(8))) short short8;
typedef __attribute__((ext_vector_type(4))) float floatx4;
typedef __hip_bfloat16 bf16;

#define DIM 768
#define NH 12
#define HD 64
#define BB 16
#define NN 640
#define BH (BB*NH)          // 192
#define MROWS (BB*NN)       // 10240
#define QKVN (3*DIM)        // 2304
#define QSCALE 0.18033688011113205f   // 0.125 * log2(e)
#define LN2SQ 0.4804530139182014f     // ln(2)^2

__device__ __forceinline__ floatx4 mfma16(short8 a, short8 b, floatx4 c) {
    return __builtin_amdgcn_mfma_f32_16x16x32_bf16(a, b, c, 0, 0, 0);
}

// async global->LDS, 16B per lane; lds dest = wave-uniform base + lane*16
__device__ __forceinline__ void async_ld16(const bf16* g, bf16* l) {
    __builtin_amdgcn_global_load_lds(
        (const __attribute__((address_space(1))) void*)g,
        (__attribute__((address_space(3))) void*)l, 16, 0, 0);
}

// truncate two f32 to bf16 and pack: lo16 = a, hi16 = b  (one v_perm_b32)
__device__ __forceinline__ unsigned pack_trunc(float a, float b) {
    return __builtin_amdgcn_perm(__float_as_uint(b), __float_as_uint(a), 0x07060302u);
}

__device__ __forceinline__ float fexp2(float x) {
#if __has_builtin(__builtin_amdgcn_exp2f)
    return __builtin_amdgcn_exp2f(x);
#else
    return exp2f(x);
#endif
}

// ---------------- prep kernels ----------------

__global__ void cvt_x(const float* __restrict__ x, bf16* __restrict__ xb, int n4) {
    int i = blockIdx.x * blockDim.x + threadIdx.x;
    if (i >= n4) return;
    float4 v = ((const float4*)x)[i];
    bf16* p = xb + (size_t)i * 4;
    p[0] = __float2bfloat16(v.x);
    p[1] = __float2bfloat16(v.y);
    p[2] = __float2bfloat16(v.z);
    p[3] = __float2bfloat16(v.w);
}

// src [R][C] fp32 -> dst [C][R] bf16 ; grid (C/32, R/32), block (32,8)
__global__ void tr_cvt(const float* __restrict__ src, bf16* __restrict__ dst, int R, int C) {
    __shared__ float tile[32][33];
    int bx = blockIdx.x, by = blockIdx.y;
    int tx = threadIdx.x, ty = threadIdx.y;
    for (int j = 0; j < 4; ++j)
        tile[ty + j*8][tx] = src[(size_t)(by*32 + ty + j*8) * C + bx*32 + tx];
    __syncthreads();
    for (int j = 0; j < 4; ++j)
        dst[(size_t)(bx*32 + ty + j*8) * R + by*32 + tx] = __float2bfloat16(tile[tx][ty + j*8]);
}

// ---------------- GEMM: C = A @ B^T  (A [M][K] bf16, B [N][K] bf16) ----------------
// BK=64: 12 barriers for K=768, 32 MFMA/barrier. LDS chunk slots XOR-swizzled
// (slot = chunk ^ (row&7)) so fragment ds_read_b128s spread over all banks.
// grid (N/128, M/128), n fastest (A-panel sharing / B in XCD L2).
// MODE 0 (qkv): bf16 out + bias, QSCALE on q cols; V cols (n0>=1536) are written
//   DIRECTLY to vT[bh][d][tok] via per-wave LDS transpose (v_tr fused away).
// MODE 1 (proj): fp32 out + bias.
template<int MODE>
__global__ __launch_bounds__(256) void gemm_bt(
    const bf16* __restrict__ A, const bf16* __restrict__ B, const float* __restrict__ bias,
    int M, int N, int K,
    bf16* __restrict__ outb, bf16* __restrict__ vTo, float* __restrict__ outf)
{
    __shared__ __align__(16) bf16 As[128*64];
    __shared__ __align__(16) bf16 Bs[128*64];

    const int t = threadIdx.x;
    const int lane = t & 63, wave = t >> 6;
    const int l15 = lane & 15, quad = lane >> 4;
    const int wm = (wave >> 1) * 64, wn = (wave & 1) * 64;
    const int m0 = blockIdx.y * 128, n0 = blockIdx.x * 128;

    floatx4 acc[4][4];
    floatx4 zero = {0.f, 0.f, 0.f, 0.f};
    for (int i = 0; i < 4; ++i)
        for (int j = 0; j < 4; ++j)
            acc[i][j] = zero;

    const int sw = l15 & 7;
    for (int kk = 0; kk < K; kk += 64) {
        __syncthreads();
        for (int s = 0; s < 4; ++s) {
            int cid = s * 256 + t;
            int row = cid >> 3;
            int gc  = ((t & 7) ^ (row & 7)) << 3;   // swizzled source chunk
            int lbase = (s * 256 + wave * 64) * 8;  // wave-uniform LDS base
            async_ld16(A + (size_t)(m0 + row) * K + kk + gc, As + lbase);
            async_ld16(B + (size_t)(n0 + row) * K + kk + gc, Bs + lbase);
        }
        __syncthreads();
        short8 af0[4], af1[4], bf0[4], bf1[4];
        for (int fm = 0; fm < 4; ++fm) {
            int base = (wm + fm*16 + l15) * 64 + ((quad ^ sw) << 3);
            af0[fm] = *(const short8*)(As + base);
            af1[fm] = *(const short8*)(As + (base ^ 32));
        }
        for (int fn = 0; fn < 4; ++fn) {
            int base = (wn + fn*16 + l15) * 64 + ((quad ^ sw) << 3);
            bf0[fn] = *(const short8*)(Bs + base);
            bf1[fn] = *(const short8*)(Bs + (base ^ 32));
        }
        for (int fm = 0; fm < 4; ++fm)
            for (int fn = 0; fn < 4; ++fn) {
                acc[fm][fn] = mfma16(af0[fm], bf0[fn], acc[fm][fn]);
                acc[fm][fn] = mfma16(af1[fm], bf1[fn], acc[fm][fn]);
            }
    }

    if (MODE == 0 && n0 >= 2*DIM) {
        // ---- V block: write vT[bh][d][tok] via per-wave LDS transpose ----
        __syncthreads();                       // done reading As -> reuse as scratch
        bf16* T4 = As + wave * 2048;           // [fm][d 16][m 32-stride]
        const int bh   = (m0 / NN) * NH + ((n0 + wn) >> 6) - 24;
        const int tokb = (m0 % NN) + wm;
        for (int fn = 0; fn < 4; ++fn) {
            int n = n0 + wn + fn*16 + l15;
            float bn = bias[n];
            for (int fm = 0; fm < 4; ++fm) {
                float v0 = acc[fm][fn][0] + bn, v1 = acc[fm][fn][1] + bn;
                float v2 = acc[fm][fn][2] + bn, v3 = acc[fm][fn][3] + bn;
                *(uint2*)(T4 + fm*512 + l15*32 + quad*4) =
                    make_uint2(pack_trunc(v0, v1), pack_trunc(v2, v3));
            }
            // lane (d=l15, seg=quad) reads T4[quad][l15][0..15], writes 32 B run
            uint4 r0 = *(const uint4*)(T4 + quad*512 + l15*32);
            uint4 r1 = *(const uint4*)(T4 + quad*512 + l15*32 + 8);
            int d = fn*16 + l15;
            bf16* dst = vTo + ((size_t)bh * HD + d) * NN + tokb + quad*16;
            *(uint4*)dst = r0;
            *(uint4*)(dst + 8) = r1;
        }
        return;
    }

    for (int fm = 0; fm < 4; ++fm) {
        for (int fn = 0; fn < 4; ++fn) {
            int n = n0 + wn + fn*16 + l15;
            float bn = bias[n];
            for (int r = 0; r < 4; ++r) {
                int m = m0 + wm + fm*16 + quad*4 + r;
                float v = acc[fm][fn][r] + bn;
                if (MODE == 0) {
                    if (n < DIM) v *= QSCALE;   // pre-scale q (incl. log2e for exp2)
                    outb[(size_t)m * N + n] = __float2bfloat16(v);
                } else {
                    outf[(size_t)m * N + n] = v;
                }
            }
        }
    }
}

// ---------------- fused attention v6: barrier-free, 16 q rows/wave ----------------
// grid (192 bh, 10 qtile): bh fastest -> a head's q-tiles share an XCD L2.
// block 256 (4 waves); wave owns 16 q rows. K/V fragments loaded DIRECTLY from
// global (L2-resident via XCD swizzle) -> NO __syncthreads anywhere: waves run
// free, 1920 blocks (7.5/CU) give the TLP to hide L2 latency. Single acc set
// keeps VGPR low for occupancy. S^T formulation; log2e folded into q; exp2;
// P packed by truncation (v_perm); per-wave LDS P round-trip (wave-ordered).
__global__ __launch_bounds__(256) void attn_kernel(
    const bf16* __restrict__ qkv, const bf16* __restrict__ vT,
    const float* __restrict__ w2, bf16* __restrict__ ao)
{
    const int bh = blockIdx.x;
    const int b = bh / NH, h = bh - b * NH;
    const int t = threadIdx.x;
    const int wave = t >> 6, lane = t & 63;
    const int l15 = lane & 15, quad = lane >> 4;
    const int qrow0 = blockIdx.y * 64 + wave * 16;

    float w0 = w2[0], w1 = w2[1];
    float wmx = fmaxf(w0, w1);
    float e0 = __expf(w0 - wmx), e1 = __expf(w1 - wmx);
    float ws0 = e0 / (e0 + e1);
    float ws1 = (1.0f - ws0) * LN2SQ;

    __shared__ __align__(16) bf16 Ps[4][16*40];
    __shared__ __align__(16) bf16 Pr[4][16*40];

    const bf16* kb = qkv + (size_t)(b*NN)*QKVN + DIM + h*HD;
    const bf16* vb = vT + (size_t)bh * HD * NN;

    const bf16* qr = qkv + (size_t)(b*NN + qrow0 + l15) * QKVN + h*HD;
    short8 aq0 = *(const short8*)(qr + quad*8);
    short8 aq1 = *(const short8*)(qr + 32 + quad*8);

    floatx4 zero = {0.f, 0.f, 0.f, 0.f};
    floatx4 accS[4], accR[4];
    for (int i = 0; i < 4; ++i) { accS[i] = zero; accR[i] = zero; }
    float lsum = 0.f;

    unsigned* PsW = (unsigned*)&Ps[wave][0];
    unsigned* PrW = (unsigned*)&Pr[wave][0];
    const int wb = l15*20 + quad*2;
    const bf16* PsR = &Ps[wave][l15*40 + quad*8];
    const bf16* PrR = &Pr[wave][l15*40 + quad*8];

    // per-lane global fragment pointers
    const bf16* kgp = kb + (size_t)l15 * QKVN + quad*8;   // K row l15, d = quad*8..
    const bf16* vgp = vb + (size_t)l15 * NN + quad*8;     // vT row d=l15, tok = quad*8..

#pragma unroll 2
    for (int kt = 0; kt < 20; ++kt) {
        // K frags (A-operand): rows kt*32 + {l15, 16+l15}, d-halves 0/32
        short8 ak0lo = *(const short8*)(kgp);
        short8 ak0hi = *(const short8*)(kgp + 32);
        short8 ak1lo = *(const short8*)(kgp + 16*QKVN);
        short8 ak1hi = *(const short8*)(kgp + 16*QKVN + 32);
        kgp += 32 * QKVN;

        // V frags (B-operand): d = dt*16+l15, tok = kt*32 + quad*8 + j
        short8 bv0 = *(const short8*)(vgp);
        short8 bv1 = *(const short8*)(vgp + 16*NN);
        short8 bv2 = *(const short8*)(vgp + 32*NN);
        short8 bv3 = *(const short8*)(vgp + 48*NN);
        vgp += 32;

        floatx4 s0 = zero, s1 = zero;                 // S'^T = S^T * log2e
        s0 = mfma16(ak0lo, aq0, s0);
        s0 = mfma16(ak0hi, aq1, s0);
        s1 = mfma16(ak1lo, aq0, s1);
        s1 = mfma16(ak1hi, aq1, s1);

        float ex0[4], ex1[4], rq0[4], rq1[4];
        for (int r = 0; r < 4; ++r) {
            ex0[r] = fexp2(s0[r]);
            ex1[r] = fexp2(s1[r]);
            float m0 = fmaxf(s0[r], 0.f), m1 = fmaxf(s1[r], 0.f);
            rq0[r] = m0 * m0;
            rq1[r] = m1 * m1;
            lsum += ex0[r] + ex1[r];
        }

        // P transpose: [16 q][32 kc] (stride 40), b64 writes, per-wave buffer
        *(uint2*)(PsW + wb)     = make_uint2(pack_trunc(ex0[0],ex0[1]), pack_trunc(ex0[2],ex0[3]));
        *(uint2*)(PsW + wb + 8) = make_uint2(pack_trunc(ex1[0],ex1[1]), pack_trunc(ex1[2],ex1[3]));
        *(uint2*)(PrW + wb)     = make_uint2(pack_trunc(rq0[0],rq0[1]), pack_trunc(rq0[2],rq0[3]));
        *(uint2*)(PrW + wb + 8) = make_uint2(pack_trunc(rq1[0],rq1[1]), pack_trunc(rq1[2],rq1[3]));

        short8 paS = *(const short8*)PsR;
        short8 paR = *(const short8*)PrR;

        accS[0] = mfma16(paS, bv0, accS[0]);  accR[0] = mfma16(paR, bv0, accR[0]);
        accS[1] = mfma16(paS, bv1, accS[1]);  accR[1] = mfma16(paR, bv1, accR[1]);
        accS[2] = mfma16(paS, bv2, accS[2]);  accR[2] = mfma16(paR, bv2, accR[2]);
        accS[3] = mfma16(paS, bv3, accS[3]);  accR[3] = mfma16(paR, bv3, accR[3]);
    }

    lsum += __shfl_xor(lsum, 16);
    lsum += __shfl_xor(lsum, 32);
    float invq[4];
    for (int r = 0; r < 4; ++r)
        invq[r] = 1.0f / __shfl(lsum, quad*4 + r);

    for (int dt = 0; dt < 4; ++dt) {
        for (int r = 0; r < 4; ++r) {
            float v = ws0 * accS[dt][r] * invq[r] + ws1 * accR[dt][r];
            int tok = qrow0 + quad*4 + r;
            ao[((size_t)(b * NN + tok)) * DIM + h * HD + dt*16 + l15] = __float2bfloat16(v);
        }
    }
}

// ---------------- launch ----------------

extern "C" void kernel_launch(void* const* d_in, const int* in_sizes, int n_in,
                              void* d_out, int out_size, void* d_ws, size_t ws_size,
                              hipStream_t stream) {
    const float* x      = (const float*)d_in[0];
    const float* qkv_w  = (const float*)d_in[1];
    const float* qkv_b  = (const float*)d_in[2];
    const float* proj_w = (const float*)d_in[3];
    const float* proj_b = (const float*)d_in[4];
    const float* w2     = (const float*)d_in[5];
    float* out = (float*)d_out;

    bf16* xb   = (bf16*)d_ws;                       // 10240*768   (reused as ao later)
    bf16* qwT  = xb   + (size_t)MROWS * DIM;        // 2304*768
    bf16* pwT  = qwT  + (size_t)QKVN * DIM;         // 768*768
    bf16* qkvb = pwT  + (size_t)DIM * DIM;          // 10240*2304 (V cols unused)
    bf16* vT   = qkvb + (size_t)MROWS * QKVN;       // 192*64*640
    bf16* ao   = xb;                                 // alias: xb dead after qkv gemm

    cvt_x<<<(MROWS * DIM / 4 + 255) / 256, 256, 0, stream>>>(x, xb, MROWS * DIM / 4);
    tr_cvt<<<dim3(QKVN / 32, DIM / 32), dim3(32, 8), 0, stream>>>(qkv_w, qwT, DIM, QKVN);
    tr_cvt<<<dim3(DIM / 32, DIM / 32), dim3(32, 8), 0, stream>>>(proj_w, pwT, DIM, DIM);

    gemm_bt<0><<<dim3(QKVN / 128, MROWS / 128), 256, 0, stream>>>(
        xb, qwT, qkv_b, MROWS, QKVN, DIM, qkvb, vT, nullptr);

    attn_kernel<<<dim3(BH, NN / 64), 256, 0, stream>>>(qkvb, vT, w2, ao);

    gemm_bt<1><<<dim3(DIM / 128, MROWS / 128), 256, 0, stream>>>(
        ao, pwT, proj_b, MROWS, DIM, DIM, nullptr, nullptr, out);
}

// Round 8
// 225.144 us; speedup vs baseline: 1.4323x; 1.4323x over previous
//
#include <hip/hip_runtime.h>
#include <hip/hip_bf16.h>

typedef __attribute__((ext_vector_type(8))) short short8;
typedef __attribute__((ext_vector_type(4))) float floatx4;
typedef __hip_bfloat16 bf16;

#define DIM 768
#define NH 12
#define HD 64
#define BB 16
#define NN 640
#define BH (BB*NH)          // 192
#define MROWS (BB*NN)       // 10240
#define QKVN (3*DIM)        // 2304
#define QSCALE 0.18033688011113205f   // 0.125 * log2(e)
#define LN2SQ 0.4804530139182014f     // ln(2)^2

__device__ __forceinline__ floatx4 mfma16(short8 a, short8 b, floatx4 c) {
    return __builtin_amdgcn_mfma_f32_16x16x32_bf16(a, b, c, 0, 0, 0);
}

// async global->LDS, 16B per lane; lds dest = wave-uniform base + lane*16
__device__ __forceinline__ void async_ld16(const bf16* g, bf16* l) {
    __builtin_amdgcn_global_load_lds(
        (const __attribute__((address_space(1))) void*)g,
        (__attribute__((address_space(3))) void*)l, 16, 0, 0);
}

// truncate two f32 to bf16 and pack: lo16 = a, hi16 = b  (one v_perm_b32)
__device__ __forceinline__ unsigned pack_trunc(float a, float b) {
    return __builtin_amdgcn_perm(__float_as_uint(b), __float_as_uint(a), 0x07060302u);
}

__device__ __forceinline__ float fexp2(float x) {
#if __has_builtin(__builtin_amdgcn_exp2f)
    return __builtin_amdgcn_exp2f(x);
#else
    return exp2f(x);
#endif
}

// ---------------- prep kernels ----------------

__global__ void cvt_x(const float* __restrict__ x, bf16* __restrict__ xb, int n4) {
    int i = blockIdx.x * blockDim.x + threadIdx.x;
    if (i >= n4) return;
    float4 v = ((const float4*)x)[i];
    bf16* p = xb + (size_t)i * 4;
    p[0] = __float2bfloat16(v.x);
    p[1] = __float2bfloat16(v.y);
    p[2] = __float2bfloat16(v.z);
    p[3] = __float2bfloat16(v.w);
}

// src [R][C] fp32 -> dst [C][R] bf16 ; grid (C/32, R/32), block (32,8)
__global__ void tr_cvt(const float* __restrict__ src, bf16* __restrict__ dst, int R, int C) {
    __shared__ float tile[32][33];
    int bx = blockIdx.x, by = blockIdx.y;
    int tx = threadIdx.x, ty = threadIdx.y;
    for (int j = 0; j < 4; ++j)
        tile[ty + j*8][tx] = src[(size_t)(by*32 + ty + j*8) * C + bx*32 + tx];
    __syncthreads();
    for (int j = 0; j < 4; ++j)
        dst[(size_t)(bx*32 + ty + j*8) * R + by*32 + tx] = __float2bfloat16(tile[tx][ty + j*8]);
}

// ---------------- GEMM: C = A @ B^T  (A [M][K] bf16, B [N][K] bf16) ----------------
// BK=64: 12 barriers for K=768, 32 MFMA/barrier. LDS chunk slots XOR-swizzled.
// grid (N/128, M/128), n fastest. MODE 0 (qkv): bf16 out + bias, QSCALE on q
// cols; V cols (n0>=1536) written directly to vT via per-wave LDS transpose.
// MODE 1 (proj): fp32 out + bias.
template<int MODE>
__global__ __launch_bounds__(256) void gemm_bt(
    const bf16* __restrict__ A, const bf16* __restrict__ B, const float* __restrict__ bias,
    int M, int N, int K,
    bf16* __restrict__ outb, bf16* __restrict__ vTo, float* __restrict__ outf)
{
    __shared__ __align__(16) bf16 As[128*64];
    __shared__ __align__(16) bf16 Bs[128*64];

    const int t = threadIdx.x;
    const int lane = t & 63, wave = t >> 6;
    const int l15 = lane & 15, quad = lane >> 4;
    const int wm = (wave >> 1) * 64, wn = (wave & 1) * 64;
    const int m0 = blockIdx.y * 128, n0 = blockIdx.x * 128;

    floatx4 acc[4][4];
    floatx4 zero = {0.f, 0.f, 0.f, 0.f};
    for (int i = 0; i < 4; ++i)
        for (int j = 0; j < 4; ++j)
            acc[i][j] = zero;

    const int sw = l15 & 7;
    for (int kk = 0; kk < K; kk += 64) {
        __syncthreads();
        for (int s = 0; s < 4; ++s) {
            int cid = s * 256 + t;
            int row = cid >> 3;
            int gc  = ((t & 7) ^ (row & 7)) << 3;   // swizzled source chunk
            int lbase = (s * 256 + wave * 64) * 8;  // wave-uniform LDS base
            async_ld16(A + (size_t)(m0 + row) * K + kk + gc, As + lbase);
            async_ld16(B + (size_t)(n0 + row) * K + kk + gc, Bs + lbase);
        }
        __syncthreads();
        short8 af0[4], af1[4], bf0[4], bf1[4];
        for (int fm = 0; fm < 4; ++fm) {
            int base = (wm + fm*16 + l15) * 64 + ((quad ^ sw) << 3);
            af0[fm] = *(const short8*)(As + base);
            af1[fm] = *(const short8*)(As + (base ^ 32));
        }
        for (int fn = 0; fn < 4; ++fn) {
            int base = (wn + fn*16 + l15) * 64 + ((quad ^ sw) << 3);
            bf0[fn] = *(const short8*)(Bs + base);
            bf1[fn] = *(const short8*)(Bs + (base ^ 32));
        }
        for (int fm = 0; fm < 4; ++fm)
            for (int fn = 0; fn < 4; ++fn) {
                acc[fm][fn] = mfma16(af0[fm], bf0[fn], acc[fm][fn]);
                acc[fm][fn] = mfma16(af1[fm], bf1[fn], acc[fm][fn]);
            }
    }

    if (MODE == 0 && n0 >= 2*DIM) {
        // ---- V block: write vT[bh][d][tok] via per-wave LDS transpose ----
        __syncthreads();                       // done reading As -> reuse as scratch
        bf16* T4 = As + wave * 2048;           // [fm][d 16][m 32-stride]
        const int bh   = (m0 / NN) * NH + ((n0 + wn) >> 6) - 24;
        const int tokb = (m0 % NN) + wm;
        for (int fn = 0; fn < 4; ++fn) {
            int n = n0 + wn + fn*16 + l15;
            float bn = bias[n];
            for (int fm = 0; fm < 4; ++fm) {
                float v0 = acc[fm][fn][0] + bn, v1 = acc[fm][fn][1] + bn;
                float v2 = acc[fm][fn][2] + bn, v3 = acc[fm][fn][3] + bn;
                *(uint2*)(T4 + fm*512 + l15*32 + quad*4) =
                    make_uint2(pack_trunc(v0, v1), pack_trunc(v2, v3));
            }
            uint4 r0 = *(const uint4*)(T4 + quad*512 + l15*32);
            uint4 r1 = *(const uint4*)(T4 + quad*512 + l15*32 + 8);
            int d = fn*16 + l15;
            bf16* dst = vTo + ((size_t)bh * HD + d) * NN + tokb + quad*16;
            *(uint4*)dst = r0;
            *(uint4*)(dst + 8) = r1;
        }
        return;
    }

    for (int fm = 0; fm < 4; ++fm) {
        for (int fn = 0; fn < 4; ++fn) {
            int n = n0 + wn + fn*16 + l15;
            float bn = bias[n];
            for (int r = 0; r < 4; ++r) {
                int m = m0 + wm + fm*16 + quad*4 + r;
                float v = acc[fm][fn][r] + bn;
                if (MODE == 0) {
                    if (n < DIM) v *= QSCALE;   // pre-scale q (incl. log2e for exp2)
                    outb[(size_t)m * N + n] = __float2bfloat16(v);
                } else {
                    outf[(size_t)m * N + n] = v;
                }
            }
        }
    }
}

// ---------------- fused attention v7: staged LDS, BK=64 ----------------
// grid (192 bh, 10 qtile): bh fastest (head's q-tiles share an XCD L2).
// block 256 (4 waves); wave owns 16 q rows. K/V tiles of 64 tokens staged
// cooperatively into double-buffered LDS (shared by all waves -> 1/4 the
// vector-memory line traffic of per-wave global loads), 10 barriers total
// with 24 MFMA each. S^T formulation; log2e folded into q; exp2; v_perm pack.
__global__ __launch_bounds__(256) void attn_kernel(
    const bf16* __restrict__ qkv, const bf16* __restrict__ vT,
    const float* __restrict__ w2, bf16* __restrict__ ao)
{
    const int bh = blockIdx.x;
    const int b = bh / NH, h = bh - b * NH;
    const int t = threadIdx.x;
    const int wave = t >> 6, lane = t & 63;
    const int l15 = lane & 15, quad = lane >> 4;
    const int qrow0 = blockIdx.y * 64 + wave * 16;

    float w0 = w2[0], w1 = w2[1];
    float wmx = fmaxf(w0, w1);
    float e0 = __expf(w0 - wmx), e1 = __expf(w1 - wmx);
    float ws0 = e0 / (e0 + e1);
    float ws1 = (1.0f - ws0) * LN2SQ;

    // K tile [64 tok][64 d], V tile [64 d][64 tok]; slot = chunk ^ (row&7)
    __shared__ __align__(16) bf16 Kb[2][64*64];
    __shared__ __align__(16) bf16 Vb[2][64*64];
    __shared__ __align__(16) bf16 Ps[4][16*72];   // [16 q][64 kc], stride 72
    __shared__ __align__(16) bf16 Pr[4][16*72];

    const bf16* kb = qkv + (size_t)(b*NN)*QKVN + DIM + h*HD;
    const bf16* vb = vT + (size_t)bh * HD * NN;

    const bf16* qr = qkv + (size_t)(b*NN + qrow0 + l15) * QKVN + h*HD;
    short8 aq0 = *(const short8*)(qr + quad*8);
    short8 aq1 = *(const short8*)(qr + 32 + quad*8);

    // staging: thread t handles rows t>>3 and 32+(t>>3); slot = lane&7;
    // source chunk gc = slot ^ (row&7), row&7 == lane>>3 for both rows.
    const int srow = t >> 3;
    const int gc   = ((lane & 7) ^ (lane >> 3)) << 3;
    const bf16* kst = kb + (size_t)srow * QKVN + gc;     // += 64*QKVN per tile
    const bf16* vst = vb + (size_t)srow * NN + gc;       // += 64 per tile
    const int lb0 = (wave * 64) * 8;                     // s=0 LDS base (elems)
    const int lb1 = (256 + wave * 64) * 8;               // s=1 LDS base

    // prologue: stage tile 0 into buf 0
    async_ld16(kst,                     &Kb[0][lb0]);
    async_ld16(kst + (size_t)32 * QKVN, &Kb[0][lb1]);
    async_ld16(vst,                     &Vb[0][lb0]);
    async_ld16(vst + (size_t)32 * NN,   &Vb[0][lb1]);

    floatx4 zero = {0.f, 0.f, 0.f, 0.f};
    floatx4 accS[4], accR[4];
    for (int i = 0; i < 4; ++i) { accS[i] = zero; accR[i] = zero; }
    float lsum = 0.f;

    const int sw = l15 & 7;
    const int fbase = l15 * 64 + ((quad ^ sw) << 3);     // K/V fragment base

    unsigned* PsW = (unsigned*)&Ps[wave][0];
    unsigned* PrW = (unsigned*)&Pr[wave][0];
    const int wb = l15*36 + quad*2;                      // uint index, + I*8
    const bf16* PsR = &Ps[wave][l15*72 + quad*8];
    const bf16* PrR = &Pr[wave][l15*72 + quad*8];

#pragma unroll 2
    for (int kt = 0; kt < 10; ++kt) {
        const int cur = kt & 1;
        __syncthreads();   // drains prefetch + protects buffer overwrite
        if (kt + 1 < 10) {
            kst += (size_t)64 * QKVN;
            vst += 64;
            async_ld16(kst,                     &Kb[cur^1][lb0]);
            async_ld16(kst + (size_t)32 * QKVN, &Kb[cur^1][lb1]);
            async_ld16(vst,                     &Vb[cur^1][lb0]);
            async_ld16(vst + (size_t)32 * NN,   &Vb[cur^1][lb1]);
        }

        const bf16* Kc = &Kb[cur][0];
        const bf16* Vc = &Vb[cur][0];

        // QK^T (S^T): 4 kc-groups of 16, each 2 MFMA over d halves
        floatx4 s[4];
        for (int I = 0; I < 4; ++I) {
            short8 aklo = *(const short8*)(Kc + fbase + I*1024);
            short8 akhi = *(const short8*)(Kc + ((fbase + I*1024) ^ 32));
            s[I] = zero;
            s[I] = mfma16(aklo, aq0, s[I]);
            s[I] = mfma16(akhi, aq1, s[I]);
        }

        // V B-frags: rows d = dt*16+l15, tok halves at chunk quad / quad^4
        short8 bvlo[4], bvhi[4];
        for (int dt = 0; dt < 4; ++dt) {
            bvlo[dt] = *(const short8*)(Vc + fbase + dt*1024);
            bvhi[dt] = *(const short8*)(Vc + ((fbase + dt*1024) ^ 32));
        }

        // softmax / relu^2 + P transpose [16 q][64 kc]
        for (int I = 0; I < 4; ++I) {
            float ex[4], rq[4];
            for (int r = 0; r < 4; ++r) {
                ex[r] = fexp2(s[I][r]);
                float m = fmaxf(s[I][r], 0.f);
                rq[r] = m * m;
                lsum += ex[r];
            }
            *(uint2*)(PsW + wb + I*8) = make_uint2(pack_trunc(ex[0],ex[1]), pack_trunc(ex[2],ex[3]));
            *(uint2*)(PrW + wb + I*8) = make_uint2(pack_trunc(rq[0],rq[1]), pack_trunc(rq[2],rq[3]));
        }

        short8 paSlo = *(const short8*)PsR;
        short8 paShi = *(const short8*)(PsR + 32);
        short8 paRlo = *(const short8*)PrR;
        short8 paRhi = *(const short8*)(PrR + 32);

        for (int dt = 0; dt < 4; ++dt) {
            accS[dt] = mfma16(paSlo, bvlo[dt], accS[dt]);
            accS[dt] = mfma16(paShi, bvhi[dt], accS[dt]);
            accR[dt] = mfma16(paRlo, bvlo[dt], accR[dt]);
            accR[dt] = mfma16(paRhi, bvhi[dt], accR[dt]);
        }
    }

    lsum += __shfl_xor(lsum, 16);
    lsum += __shfl_xor(lsum, 32);
    float invq[4];
    for (int r = 0; r < 4; ++r)
        invq[r] = 1.0f / __shfl(lsum, quad*4 + r);

    for (int dt = 0; dt < 4; ++dt) {
        for (int r = 0; r < 4; ++r) {
            float v = ws0 * accS[dt][r] * invq[r] + ws1 * accR[dt][r];
            int tok = qrow0 + quad*4 + r;
            ao[((size_t)(b * NN + tok)) * DIM + h * HD + dt*16 + l15] = __float2bfloat16(v);
        }
    }
}

// ---------------- launch ----------------

extern "C" void kernel_launch(void* const* d_in, const int* in_sizes, int n_in,
                              void* d_out, int out_size, void* d_ws, size_t ws_size,
                              hipStream_t stream) {
    const float* x      = (const float*)d_in[0];
    const float* qkv_w  = (const float*)d_in[1];
    const float* qkv_b  = (const float*)d_in[2];
    const float* proj_w = (const float*)d_in[3];
    const float* proj_b = (const float*)d_in[4];
    const float* w2     = (const float*)d_in[5];
    float* out = (float*)d_out;

    bf16* xb   = (bf16*)d_ws;                       // 10240*768   (reused as ao later)
    bf16* qwT  = xb   + (size_t)MROWS * DIM;        // 2304*768
    bf16* pwT  = qwT  + (size_t)QKVN * DIM;         // 768*768
    bf16* qkvb = pwT  + (size_t)DIM * DIM;          // 10240*2304 (V cols unused)
    bf16* vT   = qkvb + (size_t)MROWS * QKVN;       // 192*64*640
    bf16* ao   = xb;                                 // alias: xb dead after qkv gemm

    cvt_x<<<(MROWS * DIM / 4 + 255) / 256, 256, 0, stream>>>(x, xb, MROWS * DIM / 4);
    tr_cvt<<<dim3(QKVN / 32, DIM / 32), dim3(32, 8), 0, stream>>>(qkv_w, qwT, DIM, QKVN);
    tr_cvt<<<dim3(DIM / 32, DIM / 32), dim3(32, 8), 0, stream>>>(proj_w, pwT, DIM, DIM);

    gemm_bt<0><<<dim3(QKVN / 128, MROWS / 128), 256, 0, stream>>>(
        xb, qwT, qkv_b, MROWS, QKVN, DIM, qkvb, vT, nullptr);

    attn_kernel<<<dim3(BH, NN / 64), 256, 0, stream>>>(qkvb, vT, w2, ao);

    gemm_bt<1><<<dim3(DIM / 128, MROWS / 128), 256, 0, stream>>>(
        ao, pwT, proj_b, MROWS, DIM, DIM, nullptr, nullptr, out);
}

// Round 9
// 217.108 us; speedup vs baseline: 1.4854x; 1.0370x over previous
//
#include <hip/hip_runtime.h>
#include <hip/hip_bf16.h>

typedef __attribute__((ext_vector_type(8))) short short8;
typedef __attribute__((ext_vector_type(4))) float floatx4;
typedef __hip_bfloat16 bf16;

#define DIM 768
#define NH 12
#define HD 64
#define BB 16
#define NN 640
#define BH (BB*NH)          // 192
#define MROWS (BB*NN)       // 10240
#define QKVN (3*DIM)        // 2304
#define QSCALE 0.18033688011113205f   // 0.125 * log2(e)
#define LN2SQ 0.4804530139182014f     // ln(2)^2

#define CVT_BLK (MROWS*DIM/4/256)     // 7680
#define TRQ_BLK ((QKVN/32)*(DIM/32))  // 1728
#define TRP_BLK ((DIM/32)*(DIM/32))   // 576

__device__ __forceinline__ floatx4 mfma16(short8 a, short8 b, floatx4 c) {
    return __builtin_amdgcn_mfma_f32_16x16x32_bf16(a, b, c, 0, 0, 0);
}

// async global->LDS, 16B per lane; lds dest = wave-uniform base + lane*16
__device__ __forceinline__ void async_ld16(const bf16* g, bf16* l) {
    __builtin_amdgcn_global_load_lds(
        (const __attribute__((address_space(1))) void*)g,
        (__attribute__((address_space(3))) void*)l, 16, 0, 0);
}

// truncate two f32 to bf16 and pack: lo16 = a, hi16 = b  (one v_perm_b32)
__device__ __forceinline__ unsigned pack_trunc(float a, float b) {
    return __builtin_amdgcn_perm(__float_as_uint(b), __float_as_uint(a), 0x07060302u);
}

__device__ __forceinline__ float fexp2(float x) {
#if __has_builtin(__builtin_amdgcn_exp2f)
    return __builtin_amdgcn_exp2f(x);
#else
    return exp2f(x);
#endif
}

// ---------------- fused prep: x->bf16 + both weight transposes ----------------
// grid CVT_BLK + TRQ_BLK + TRP_BLK blocks of 256
__global__ void prep_all(const float* __restrict__ x,
                         const float* __restrict__ qkv_w,
                         const float* __restrict__ proj_w,
                         bf16* __restrict__ xb,
                         bf16* __restrict__ qwT,
                         bf16* __restrict__ pwT)
{
    __shared__ float tile[32][33];
    const int id = blockIdx.x;
    const int t = threadIdx.x;

    if (id < CVT_BLK) {
        int i = id * 256 + t;
        float4 v = ((const float4*)x)[i];
        bf16* p = xb + (size_t)i * 4;
        p[0] = __float2bfloat16(v.x);
        p[1] = __float2bfloat16(v.y);
        p[2] = __float2bfloat16(v.z);
        p[3] = __float2bfloat16(v.w);
        return;
    }

    const float* src; bf16* dst; int C, bx, by;
    if (id < CVT_BLK + TRQ_BLK) {
        int j = id - CVT_BLK;
        bx = j % (QKVN/32); by = j / (QKVN/32);
        src = qkv_w; dst = qwT; C = QKVN;
    } else {
        int j = id - CVT_BLK - TRQ_BLK;
        bx = j % (DIM/32); by = j / (DIM/32);
        src = proj_w; dst = pwT; C = DIM;
    }
    const int R = DIM;
    const int tx = t & 31, ty = t >> 5;
    for (int j = 0; j < 4; ++j)
        tile[ty + j*8][tx] = src[(size_t)(by*32 + ty + j*8) * C + bx*32 + tx];
    __syncthreads();
    for (int j = 0; j < 4; ++j)
        dst[(size_t)(bx*32 + ty + j*8) * R + by*32 + tx] = __float2bfloat16(tile[tx][ty + j*8]);
}

// ---------------- GEMM: C = A @ B^T  (A [M][K] bf16, B [N][K] bf16) ----------------
// Double-buffered BK=64: ONE barrier per iter, prefetch for tile k+1 issued at
// the top of tile k's compute (~full compute phase of latency head start).
// K must be a multiple of 128 (even iter count) for the V-scratch reuse below.
// LDS chunk slots XOR-swizzled (slot = chunk ^ (row&7)).
// grid (N/128, M/128), n fastest. MODE 0 (qkv): bf16 out + bias, QSCALE on q
// cols; V cols (n0>=1536) written directly to vT via per-wave LDS transpose.
// MODE 1 (proj): fp32 out + bias.
template<int MODE>
__global__ __launch_bounds__(256) void gemm_bt(
    const bf16* __restrict__ A, const bf16* __restrict__ B, const float* __restrict__ bias,
    int M, int N, int K,
    bf16* __restrict__ outb, bf16* __restrict__ vTo, float* __restrict__ outf)
{
    __shared__ __align__(16) bf16 As[2][128*64];
    __shared__ __align__(16) bf16 Bs[2][128*64];

    const int t = threadIdx.x;
    const int lane = t & 63, wave = t >> 6;
    const int l15 = lane & 15, quad = lane >> 4;
    const int wm = (wave >> 1) * 64, wn = (wave & 1) * 64;
    const int m0 = blockIdx.y * 128, n0 = blockIdx.x * 128;

    floatx4 acc[4][4];
    floatx4 zero = {0.f, 0.f, 0.f, 0.f};
    for (int i = 0; i < 4; ++i)
        for (int j = 0; j < 4; ++j)
            acc[i][j] = zero;

    // staging: thread handles rows s*32 + (t>>3), s=0..3; slot = t&7;
    // source chunk = slot ^ (row&7); row&7 == (t>>3)&7 (s*32 = 0 mod 8).
    const int trow = t >> 3;
    const int gc = ((t & 7) ^ (trow & 7)) << 3;
    const bf16* aA = A + (size_t)(m0 + trow) * K + gc;
    const bf16* aB = B + (size_t)(n0 + trow) * K + gc;
    const int lb = wave * 512;   // wave-uniform LDS element base within a 256-chunk group

    // prologue: stage tile 0 into buf 0
    for (int s = 0; s < 4; ++s) {
        async_ld16(aA + (size_t)s*32*K, &As[0][s*2048 + lb]);
        async_ld16(aB + (size_t)s*32*K, &Bs[0][s*2048 + lb]);
    }

    const int sw = l15 & 7;
    const int nit = K >> 6;
    for (int kt = 0; kt < nit; ++kt) {
        const int cur = kt & 1;
        __syncthreads();   // drains prefetch into buf cur; protects buf cur^1 overwrite
        if (kt + 1 < nit) {
            const bf16* pA = aA + (size_t)(kt+1)*64;
            const bf16* pB = aB + (size_t)(kt+1)*64;
            for (int s = 0; s < 4; ++s) {
                async_ld16(pA + (size_t)s*32*K, &As[cur^1][s*2048 + lb]);
                async_ld16(pB + (size_t)s*32*K, &Bs[cur^1][s*2048 + lb]);
            }
        }
        short8 af0[4], af1[4], bf0[4], bf1[4];
        for (int fm = 0; fm < 4; ++fm) {
            int base = (wm + fm*16 + l15) * 64 + ((quad ^ sw) << 3);
            af0[fm] = *(const short8*)(&As[cur][base]);
            af1[fm] = *(const short8*)(&As[cur][base ^ 32]);
        }
        for (int fn = 0; fn < 4; ++fn) {
            int base = (wn + fn*16 + l15) * 64 + ((quad ^ sw) << 3);
            bf0[fn] = *(const short8*)(&Bs[cur][base]);
            bf1[fn] = *(const short8*)(&Bs[cur][base ^ 32]);
        }
        for (int fm = 0; fm < 4; ++fm)
            for (int fn = 0; fn < 4; ++fn) {
                acc[fm][fn] = mfma16(af0[fm], bf0[fn], acc[fm][fn]);
                acc[fm][fn] = mfma16(af1[fm], bf1[fn], acc[fm][fn]);
            }
    }

    if (MODE == 0 && n0 >= 2*DIM) {
        // ---- V block: write vT[bh][d][tok] via per-wave LDS transpose ----
        // nit even -> last compute read buf 1; buf 0 idle since the kt=nit-1
        // barrier, safe as per-wave scratch (4 waves x 2048 = 8192 = buf size).
        bf16* T4 = &As[0][0] + wave * 2048;    // [fm][d 16][m 32-stride]
        const int bh   = (m0 / NN) * NH + ((n0 + wn) >> 6) - 24;
        const int tokb = (m0 % NN) + wm;
        for (int fn = 0; fn < 4; ++fn) {
            int n = n0 + wn + fn*16 + l15;
            float bn = bias[n];
            for (int fm = 0; fm < 4; ++fm) {
                float v0 = acc[fm][fn][0] + bn, v1 = acc[fm][fn][1] + bn;
                float v2 = acc[fm][fn][2] + bn, v3 = acc[fm][fn][3] + bn;
                *(uint2*)(T4 + fm*512 + l15*32 + quad*4) =
                    make_uint2(pack_trunc(v0, v1), pack_trunc(v2, v3));
            }
            uint4 r0 = *(const uint4*)(T4 + quad*512 + l15*32);
            uint4 r1 = *(const uint4*)(T4 + quad*512 + l15*32 + 8);
            int d = fn*16 + l15;
            bf16* dst = vTo + ((size_t)bh * HD + d) * NN + tokb + quad*16;
            *(uint4*)dst = r0;
            *(uint4*)(dst + 8) = r1;
        }
        return;
    }

    for (int fm = 0; fm < 4; ++fm) {
        for (int fn = 0; fn < 4; ++fn) {
            int n = n0 + wn + fn*16 + l15;
            float bn = bias[n];
            for (int r = 0; r < 4; ++r) {
                int m = m0 + wm + fm*16 + quad*4 + r;
                float v = acc[fm][fn][r] + bn;
                if (MODE == 0) {
                    if (n < DIM) v *= QSCALE;   // pre-scale q (incl. log2e for exp2)
                    outb[(size_t)m * N + n] = __float2bfloat16(v);
                } else {
                    outf[(size_t)m * N + n] = v;
                }
            }
        }
    }
}

// ---------------- fused attention v7: staged LDS, BK=64 ----------------
// grid (192 bh, 10 qtile): bh fastest (head's q-tiles share an XCD L2).
// block 256 (4 waves); wave owns 16 q rows. K/V tiles of 64 tokens staged
// cooperatively into double-buffered LDS, one barrier/iter, 24 MFMA each.
// S^T formulation; log2e folded into q; exp2; v_perm pack.
__global__ __launch_bounds__(256) void attn_kernel(
    const bf16* __restrict__ qkv, const bf16* __restrict__ vT,
    const float* __restrict__ w2, bf16* __restrict__ ao)
{
    const int bh = blockIdx.x;
    const int b = bh / NH, h = bh - b * NH;
    const int t = threadIdx.x;
    const int wave = t >> 6, lane = t & 63;
    const int l15 = lane & 15, quad = lane >> 4;
    const int qrow0 = blockIdx.y * 64 + wave * 16;

    float w0 = w2[0], w1 = w2[1];
    float wmx = fmaxf(w0, w1);
    float e0 = __expf(w0 - wmx), e1 = __expf(w1 - wmx);
    float ws0 = e0 / (e0 + e1);
    float ws1 = (1.0f - ws0) * LN2SQ;

    // K tile [64 tok][64 d], V tile [64 d][64 tok]; slot = chunk ^ (row&7)
    __shared__ __align__(16) bf16 Kb[2][64*64];
    __shared__ __align__(16) bf16 Vb[2][64*64];
    __shared__ __align__(16) bf16 Ps[4][16*72];   // [16 q][64 kc], stride 72
    __shared__ __align__(16) bf16 Pr[4][16*72];

    const bf16* kb = qkv + (size_t)(b*NN)*QKVN + DIM + h*HD;
    const bf16* vb = vT + (size_t)bh * HD * NN;

    const bf16* qr = qkv + (size_t)(b*NN + qrow0 + l15) * QKVN + h*HD;
    short8 aq0 = *(const short8*)(qr + quad*8);
    short8 aq1 = *(const short8*)(qr + 32 + quad*8);

    const int srow = t >> 3;
    const int gc   = ((lane & 7) ^ (lane >> 3)) << 3;
    const bf16* kst = kb + (size_t)srow * QKVN + gc;     // += 64*QKVN per tile
    const bf16* vst = vb + (size_t)srow * NN + gc;       // += 64 per tile
    const int lb0 = (wave * 64) * 8;
    const int lb1 = (256 + wave * 64) * 8;

    async_ld16(kst,                     &Kb[0][lb0]);
    async_ld16(kst + (size_t)32 * QKVN, &Kb[0][lb1]);
    async_ld16(vst,                     &Vb[0][lb0]);
    async_ld16(vst + (size_t)32 * NN,   &Vb[0][lb1]);

    floatx4 zero = {0.f, 0.f, 0.f, 0.f};
    floatx4 accS[4], accR[4];
    for (int i = 0; i < 4; ++i) { accS[i] = zero; accR[i] = zero; }
    float lsum = 0.f;

    const int sw = l15 & 7;
    const int fbase = l15 * 64 + ((quad ^ sw) << 3);

    unsigned* PsW = (unsigned*)&Ps[wave][0];
    unsigned* PrW = (unsigned*)&Pr[wave][0];
    const int wb = l15*36 + quad*2;
    const bf16* PsR = &Ps[wave][l15*72 + quad*8];
    const bf16* PrR = &Pr[wave][l15*72 + quad*8];

#pragma unroll 2
    for (int kt = 0; kt < 10; ++kt) {
        const int cur = kt & 1;
        __syncthreads();
        if (kt + 1 < 10) {
            kst += (size_t)64 * QKVN;
            vst += 64;
            async_ld16(kst,                     &Kb[cur^1][lb0]);
            async_ld16(kst + (size_t)32 * QKVN, &Kb[cur^1][lb1]);
            async_ld16(vst,                     &Vb[cur^1][lb0]);
            async_ld16(vst + (size_t)32 * NN,   &Vb[cur^1][lb1]);
        }

        const bf16* Kc = &Kb[cur][0];
        const bf16* Vc = &Vb[cur][0];

        floatx4 s[4];
        for (int I = 0; I < 4; ++I) {
            short8 aklo = *(const short8*)(Kc + fbase + I*1024);
            short8 akhi = *(const short8*)(Kc + ((fbase + I*1024) ^ 32));
            s[I] = zero;
            s[I] = mfma16(aklo, aq0, s[I]);
            s[I] = mfma16(akhi, aq1, s[I]);
        }

        short8 bvlo[4], bvhi[4];
        for (int dt = 0; dt < 4; ++dt) {
            bvlo[dt] = *(const short8*)(Vc + fbase + dt*1024);
            bvhi[dt] = *(const short8*)(Vc + ((fbase + dt*1024) ^ 32));
        }

        for (int I = 0; I < 4; ++I) {
            float ex[4], rq[4];
            for (int r = 0; r < 4; ++r) {
                ex[r] = fexp2(s[I][r]);
                float m = fmaxf(s[I][r], 0.f);
                rq[r] = m * m;
                lsum += ex[r];
            }
            *(uint2*)(PsW + wb + I*8) = make_uint2(pack_trunc(ex[0],ex[1]), pack_trunc(ex[2],ex[3]));
            *(uint2*)(PrW + wb + I*8) = make_uint2(pack_trunc(rq[0],rq[1]), pack_trunc(rq[2],rq[3]));
        }

        short8 paSlo = *(const short8*)PsR;
        short8 paShi = *(const short8*)(PsR + 32);
        short8 paRlo = *(const short8*)PrR;
        short8 paRhi = *(const short8*)(PrR + 32);

        for (int dt = 0; dt < 4; ++dt) {
            accS[dt] = mfma16(paSlo, bvlo[dt], accS[dt]);
            accS[dt] = mfma16(paShi, bvhi[dt], accS[dt]);
            accR[dt] = mfma16(paRlo, bvlo[dt], accR[dt]);
            accR[dt] = mfma16(paRhi, bvhi[dt], accR[dt]);
        }
    }

    lsum += __shfl_xor(lsum, 16);
    lsum += __shfl_xor(lsum, 32);
    float invq[4];
    for (int r = 0; r < 4; ++r)
        invq[r] = 1.0f / __shfl(lsum, quad*4 + r);

    for (int dt = 0; dt < 4; ++dt) {
        for (int r = 0; r < 4; ++r) {
            float v = ws0 * accS[dt][r] * invq[r] + ws1 * accR[dt][r];
            int tok = qrow0 + quad*4 + r;
            ao[((size_t)(b * NN + tok)) * DIM + h * HD + dt*16 + l15] = __float2bfloat16(v);
        }
    }
}

// ---------------- launch ----------------

extern "C" void kernel_launch(void* const* d_in, const int* in_sizes, int n_in,
                              void* d_out, int out_size, void* d_ws, size_t ws_size,
                              hipStream_t stream) {
    const float* x      = (const float*)d_in[0];
    const float* qkv_w  = (const float*)d_in[1];
    const float* qkv_b  = (const float*)d_in[2];
    const float* proj_w = (const float*)d_in[3];
    const float* proj_b = (const float*)d_in[4];
    const float* w2     = (const float*)d_in[5];
    float* out = (float*)d_out;

    bf16* xb   = (bf16*)d_ws;                       // 10240*768   (reused as ao later)
    bf16* qwT  = xb   + (size_t)MROWS * DIM;        // 2304*768
    bf16* pwT  = qwT  + (size_t)QKVN * DIM;         // 768*768
    bf16* qkvb = pwT  + (size_t)DIM * DIM;          // 10240*2304 (V cols unused)
    bf16* vT   = qkvb + (size_t)MROWS * QKVN;       // 192*64*640
    bf16* ao   = xb;                                 // alias: xb dead after qkv gemm

    prep_all<<<CVT_BLK + TRQ_BLK + TRP_BLK, 256, 0, stream>>>(
        x, qkv_w, proj_w, xb, qwT, pwT);

    gemm_bt<0><<<dim3(QKVN / 128, MROWS / 128), 256, 0, stream>>>(
        xb, qwT, qkv_b, MROWS, QKVN, DIM, qkvb, vT, nullptr);

    attn_kernel<<<dim3(BH, NN / 64), 256, 0, stream>>>(qkvb, vT, w2, ao);

    gemm_bt<1><<<dim3(DIM / 128, MROWS / 128), 256, 0, stream>>>(
        ao, pwT, proj_b, MROWS, DIM, DIM, nullptr, nullptr, out);
}